// Round 8
// baseline (1085.863 us; speedup 1.0000x reference)
//
#include <hip/hip_runtime.h>
#include <hip/hip_bf16.h>

// B=2, H=96, W=128, D=64, C=32, F=32, kernel 3x3x3, pad 1 in h/w, depth-shifted.
#define Bn 2
#define Hn 96
#define Wn 128
#define Dn 64
#define Cn 32
#define Fn 32
#define TW 8                 // patch width (one wave per pixel, 2x8 patch = 16 waves)
#define CWn 10               // staged w-cols (w0-1 .. w0+8)
#define HCn 12               // h-rows per persistent block (6 patches of 2)
#define NP 6
#define COLSZ (Dn * Cn)      // 2048 shorts per column

typedef short bf16x8 __attribute__((ext_vector_type(8)));
typedef float f32x4  __attribute__((ext_vector_type(4)));

__device__ __forceinline__ ushort f2bf(float x) {
    __hip_bfloat16 h = __float2bfloat16(x);   // RNE
    return *reinterpret_cast<ushort*>(&h);
}

// Rows are 32 shorts (64B) = 4 slots of 16B. slot' = slot ^ ((r>>1)&3):
// 16 consecutive rows at one slot spread over all 8 bank-quads (2-way = free).
// XOR term invariant under row += 16 -> fragment offsets step by +-512 shorts.
__device__ __forceinline__ int swz_off(int r, int slot) {
    return r * 32 + ((slot ^ ((r >> 1) & 3)) << 3);
}

// ---- prep: transpose kernel weights to bf16 kT[27][f][c] in workspace
__global__ void prep_kT(const float* __restrict__ kern, ushort* __restrict__ kT) {
    const int e = blockIdx.x * 256 + threadIdx.x;    // 27*32*32 = 27648
    if (e >= 27 * Cn * Fn) return;
    const int c  = e & 31;
    const int f  = (e >> 5) & 31;
    const int kk = e >> 10;
    kT[e] = f2bf(kern[kk * (Cn * Fn) + c * Fn + f]);
}

__global__ __launch_bounds__(1024, 4) void sconv3d_ring(
    const float*  __restrict__ img,   // [B,H,W,D,C]
    const int*    __restrict__ bp,    // [B,H,W]
    const float*  __restrict__ kern,  // [3,3,3,C,F] (fp32, for dv path)
    const ushort* __restrict__ kT,    // [27][F][C] bf16
    const float*  __restrict__ dvp,
    float*        __restrict__ out)   // [B,H,W,D,F]
{
    // 4-row ring x 10 w-cols, bf16 [slot][wc][d][c], swizzled 16B slots. 160 KB.
    // image row r lives in slot (r+1)&3.
    __shared__ ushort colS[4 * CWn * COLSZ];

    const int bid = blockIdx.x;                      // 256 blocks: b(1) hk(3) wt(4)
    const int wt  = bid & 15;
    const int hk  = (bid >> 4) & 7;
    const int b   = bid >> 7;
    const int hc  = hk * HCn;                        // multiple of 4
    const int w0  = wt * TW;

    const int tid  = threadIdx.x;
    const int lane = tid & 63;
    const int wave = tid >> 6;                       // 0..15
    const int ph   = wave >> 3;                      // 0..1
    const int pw   = wave & 7;                       // 0..7
    const int w    = w0 + pw;

    const int lrow = lane & 15;                      // A row (d in 16) / B f-col
    const int lgrp = lane >> 4;                      // 16B k-slot (c-block)

    const float dv = *dvp;

    // ---- prologue: stage rows hc-1..hc+2 (40 cols); OOB -> zeros (keeps A finite)
#pragma unroll
    for (int it = 0; it < 20; ++it) {
        const int e  = it * 1024 + tid;
        const int jl = e >> 9;                       // 0..39
        const int sl = e & 511;
        const int row = hc - 1 + jl / CWn;
        const int wc  = jl % CWn;
        const int ww  = w0 - 1 + wc;
        const bool v  = (row >= 0) && (row < Hn) && (ww >= 0) && (ww < Wn);
        float4 x = make_float4(0.f, 0.f, 0.f, 0.f);
        if (v) x = *(const float4*)(img + (size_t)((b * Hn + row) * Wn + ww) * COLSZ + sl * 4);
        ushort4 u;
        u.x = f2bf(x.x); u.y = f2bf(x.y); u.z = f2bf(x.z); u.w = f2bf(x.w);
        *(ushort4*)&colS[((((row + 1) & 3) * CWn) + wc) * COLSZ
                         + swz_off(sl >> 3, (sl >> 1) & 3) + (sl & 1) * 4] = u;
    }
    __syncthreads();

    for (int p = 0; p < NP; ++p) {
        const int h0 = hc + 2 * p;
        const int h  = h0 + ph;
        const int bpc = bp[(b * Hn + h) * Wn + w];

        int  sh[9];
        bool tv[9];
#pragma unroll
        for (int kh = 0; kh < 3; ++kh)
#pragma unroll
            for (int kw = 0; kw < 3; ++kw) {
                const int hh = h - 1 + kh;
                const int ww = w - 1 + kw;
                const bool v = (hh >= 0) && (hh < Hn) && (ww >= 0) && (ww < Wn);
                tv[kh * 3 + kw] = v;
                sh[kh * 3 + kw] = v ? (bpc - bp[(b * Hn + hh) * Wn + ww]) : 0;
            }

        f32x4 acc[4][2];
#pragma unroll
        for (int i = 0; i < 4; ++i)
#pragma unroll
            for (int j = 0; j < 2; ++j) acc[i][j] = (f32x4)0.f;

        // branchless tap group: invalid tap -> B zeroed (A always finite: zero-staged)
        auto tapg = [&](int kh, int kw) {
            const int  t = kh * 3 + kw;
            const int  s = sh[t];
            const bool v = tv[t];
            const int  hh = h - 1 + kh;
            const ushort* colp = &colS[((((hh + 1) & 3) * CWn) + (pw + kw)) * COLSZ];
            const int kkb = t * 3;
            bf16x8 bfr[3][2];
#pragma unroll
            for (int kd = 0; kd < 3; ++kd) {
                const bf16x8 b0 = *(const bf16x8*)&kT[((kkb + kd) * Fn + lrow)      * Cn + lgrp * 8];
                const bf16x8 b1 = *(const bf16x8*)&kT[((kkb + kd) * Fn + lrow + 16) * Cn + lgrp * 8];
                bfr[kd][0] = v ? b0 : (bf16x8)0;
                bfr[kd][1] = v ? b1 : (bf16x8)0;
            }
            __builtin_amdgcn_s_setprio(1);
#pragma unroll
            for (int kd = 0; kd < 3; ++kd) {
                const int i1 = 16 + lrow + s + kd - 1;   // in [0,47] (|s|<=15)
                const int o1 = swz_off(i1, lgrp);
                const bf16x8 a1 = *(const bf16x8*)&colp[o1];
                acc[1][0] = __builtin_amdgcn_mfma_f32_16x16x32_bf16(a1, bfr[kd][0], acc[1][0], 0, 0, 0);
                acc[1][1] = __builtin_amdgcn_mfma_f32_16x16x32_bf16(a1, bfr[kd][1], acc[1][1], 0, 0, 0);
                const bf16x8 a2 = *(const bf16x8*)&colp[o1 + 512];
                acc[2][0] = __builtin_amdgcn_mfma_f32_16x16x32_bf16(a2, bfr[kd][0], acc[2][0], 0, 0, 0);
                acc[2][1] = __builtin_amdgcn_mfma_f32_16x16x32_bf16(a2, bfr[kd][1], acc[2][1], 0, 0, 0);
                {
                    const bool vv = (i1 >= 16);          // dt=0 depth-valid
                    bf16x8 a0 = *(const bf16x8*)&colp[vv ? o1 - 512 : o1];
                    if (!vv) a0 = (bf16x8)0;
                    acc[0][0] = __builtin_amdgcn_mfma_f32_16x16x32_bf16(a0, bfr[kd][0], acc[0][0], 0, 0, 0);
                    acc[0][1] = __builtin_amdgcn_mfma_f32_16x16x32_bf16(a0, bfr[kd][1], acc[0][1], 0, 0, 0);
                }
                {
                    const bool vv = (i1 <= 31);          // dt=3 depth-valid
                    bf16x8 a3 = *(const bf16x8*)&colp[vv ? o1 + 1024 : o1];
                    if (!vv) a3 = (bf16x8)0;
                    acc[3][0] = __builtin_amdgcn_mfma_f32_16x16x32_bf16(a3, bfr[kd][0], acc[3][0], 0, 0, 0);
                    acc[3][1] = __builtin_amdgcn_mfma_f32_16x16x32_bf16(a3, bfr[kd][1], acc[3][1], 0, 0, 0);
                }
            }
            __builtin_amdgcn_s_setprio(0);
        };

        tapg(0, 0); tapg(0, 1); tapg(0, 2);
        tapg(1, 0); tapg(1, 1); tapg(1, 2);
        __syncthreads();   // slots of rows h0-1,h0 now free (kh=2 reads h0+1,h0+2 only)

#define ISSUE(q, it) {                                                          \
        const int e = (it) * 1024 + tid; const int jl = e >> 9;                 \
        const int sl_ = e & 511;                                               \
        const int row = r0 + (jl >= CWn); const int ww2 = w0 - 1 + (jl % CWn); \
        const bool v2 = (row < Hn) && (ww2 >= 0) && (ww2 < Wn);                \
        pv[q] = v2 ? *(const float4*)(img + (size_t)((b * Hn + row) * Wn + ww2) * COLSZ + sl_ * 4) \
                   : make_float4(0.f, 0.f, 0.f, 0.f); }
#define COMMIT(q, it) {                                                         \
        const int e = (it) * 1024 + tid; const int jl = e >> 9;                 \
        const int sl_ = e & 511;                                               \
        const int row = r0 + (jl >= CWn); const int wc2 = jl % CWn;            \
        ushort4 u; u.x = f2bf(pv[q].x); u.y = f2bf(pv[q].y);                   \
        u.z = f2bf(pv[q].z); u.w = f2bf(pv[q].w);                              \
        *(ushort4*)&colS[((((row + 1) & 3) * CWn) + wc2) * COLSZ               \
                         + swz_off(sl_ >> 3, (sl_ >> 1) & 3) + (sl_ & 1) * 4] = u; }

        if (p < NP - 1) {
            // stage rows h0+3, h0+4 (20 cols) in 3 batches interleaved with kh=2
            const int r0 = h0 + 3;
            float4 pv[4];
            ISSUE(0, 0) ISSUE(1, 1) ISSUE(2, 2) ISSUE(3, 3)
            tapg(2, 0);
            COMMIT(0, 0) COMMIT(1, 1) COMMIT(2, 2) COMMIT(3, 3)
            ISSUE(0, 4) ISSUE(1, 5) ISSUE(2, 6)
            tapg(2, 1);
            COMMIT(0, 4) COMMIT(1, 5) COMMIT(2, 6)
            ISSUE(0, 7) ISSUE(1, 8) ISSUE(2, 9)
            tapg(2, 2);
            COMMIT(0, 7) COMMIT(1, 8) COMMIT(2, 9)
        } else {
            tapg(2, 0); tapg(2, 1); tapg(2, 2);
        }
#undef ISSUE
#undef COMMIT

        // ---- dv != 0 correction (dead for this benchmark; keeps semantics general)
        if (dv != 0.0f) {
#pragma unroll
            for (int kh = 0; kh < 3; ++kh)
#pragma unroll
                for (int kw = 0; kw < 3; ++kw) {
                    const bool sp = tv[kh * 3 + kw];
                    const int  s  = sh[kh * 3 + kw];
                    for (int kd = 0; kd < 3; ++kd) {
                        float ks0 = 0.f, ks1 = 0.f;
                        for (int c = 0; c < Cn; ++c) {
                            const float* kp = kern + (size_t)(((kh * 3 + kw) * 3 + kd) * Cn + c) * Fn;
                            ks0 += kp[lrow];
                            ks1 += kp[16 + lrow];
                        }
                        for (int dt = 0; dt < 4; ++dt)
                            for (int j = 0; j < 4; ++j) {
                                const int d   = dt * 16 + lgrp * 4 + j;
                                const int idx = d + s + kd - 1;
                                const bool valid = sp && (idx >= 0) && (idx < Dn);
                                if (!valid) { acc[dt][0][j] += dv * ks0; acc[dt][1][j] += dv * ks1; }
                            }
                    }
                }
        }

        // ---- store: D lane l reg j -> d = dt*16 + lgrp*4 + j, f = ft*16 + lrow
        const size_t pixbase = ((size_t)(b * Hn + h) * Wn + w) * (Dn * Fn);
#pragma unroll
        for (int dt = 0; dt < 4; ++dt)
#pragma unroll
            for (int ft = 0; ft < 2; ++ft)
#pragma unroll
                for (int j = 0; j < 4; ++j) {
                    const int d = dt * 16 + lgrp * 4 + j;
                    const int f = ft * 16 + lrow;
                    out[pixbase + d * Fn + f] = acc[dt][ft][j];
                }

        if (p < NP - 1) __syncthreads();   // staged rows visible before next patch
    }
}

extern "C" void kernel_launch(void* const* d_in, const int* in_sizes, int n_in,
                              void* d_out, int out_size, void* d_ws, size_t ws_size,
                              hipStream_t stream) {
    const float* img  = (const float*)d_in[0];
    const int*   bp   = (const int*)d_in[1];
    const float* kern = (const float*)d_in[2];
    const float* dvp  = (const float*)d_in[3];
    float* out = (float*)d_out;
    ushort* kT = (ushort*)d_ws;                      // 27*32*32*2 = 55296 B

    hipLaunchKernelGGL(prep_kT, dim3(108), dim3(256), 0, stream, kern, kT);

    const int nblk = Bn * (Hn / HCn) * (Wn / TW);    // 2*8*16 = 256 (1 per CU)
    hipLaunchKernelGGL(sconv3d_ring, dim3(nblk), dim3(1024), 0, stream,
                       img, bp, kern, kT, dvp, out);
}

// Round 9
// 971.795 us; speedup vs baseline: 1.1174x; 1.1174x over previous
//
#include <hip/hip_runtime.h>
#include <hip/hip_bf16.h>

// B=2, H=96, W=128, D=64, C=32, F=32, kernel 3x3x3, pad 1 in h/w, depth-shifted.
#define Bn 2
#define Hn 96
#define Wn 128
#define Dn 64
#define Cn 32
#define Fn 32
#define THp 3                // pixel rows per patch
#define TWp 4                // pixel cols per patch (12 pixels = 12 consumer waves)
#define CWc 6                // halo cols (TWp+2)
#define NP 8                 // patches per block (walks 24 h-rows)
#define COLSZ (Dn * Cn)      // 2048 shorts per column

typedef short bf16x8 __attribute__((ext_vector_type(8)));
typedef float f32x4  __attribute__((ext_vector_type(4)));

__device__ __forceinline__ ushort f2bf(float x) {
    __hip_bfloat16 h = __float2bfloat16(x);   // RNE
    return *reinterpret_cast<ushort*>(&h);
}

// Rows are 32 shorts (64B) = 4 slots of 16B. slot' = slot ^ ((r>>1)&3):
// 16 consecutive rows at one slot spread over all 8 bank-quads (2-way = free).
// XOR term invariant under row += 16 -> fragment offsets step by +-512 shorts.
__device__ __forceinline__ int swz_off(int r, int slot) {
    return r * 32 + ((slot ^ ((r >> 1) & 3)) << 3);
}
// ring slot of image row r (valid for r >= -1)
__device__ __forceinline__ int slot6(int r) { return (int)((unsigned)(r + 6) % 6u); }

// ---- prep: transpose kernel weights to bf16 kT[27][f][c] in workspace
__global__ void prep_kT(const float* __restrict__ kern, ushort* __restrict__ kT) {
    const int e = blockIdx.x * 256 + threadIdx.x;    // 27*32*32 = 27648
    if (e >= 27 * Cn * Fn) return;
    const int c  = e & 31;
    const int f  = (e >> 5) & 31;
    const int kk = e >> 10;
    kT[e] = f2bf(kern[kk * (Cn * Fn) + c * Fn + f]);
}

__global__ __launch_bounds__(1024, 4) void sconv3d_pc(
    const float*  __restrict__ img,   // [B,H,W,D,C]
    const int*    __restrict__ bp,    // [B,H,W]
    const float*  __restrict__ kern,  // [3,3,3,C,F] (fp32, dv path only)
    const ushort* __restrict__ kT,    // [27][F][C] bf16
    const float*  __restrict__ dvp,
    float*        __restrict__ out)   // [B,H,W,D,F]
{
    // 6-slot h-row ring x 6 w-cols, bf16 [slot][wc][d][c], swizzled. 147456 B.
    __shared__ ushort colS[6 * CWc * COLSZ];

    const int bid = blockIdx.x;                      // 256 blocks: b(1) hk(2b) wt(5b)
    const int wt  = bid & 31;
    const int hk  = (bid >> 5) & 3;
    const int b   = bid >> 7;
    const int hc  = hk * (THp * NP);                 // 0,24,48,72
    const int w0  = wt * TWp;

    const int tid  = threadIdx.x;
    const int lane = tid & 63;
    const int wave = tid >> 6;                       // 0..15
    const bool consumer = (wave < 12);
    const int ph   = wave >> 2;                      // consumer pixel row 0..2
    const int pw   = wave & 3;                       // consumer pixel col 0..3
    const int lrow = lane & 15;                      // A row (d in 16) / B f-col
    const int lgrp = lane >> 4;                      // 16B k-slot (c-block)
    const int ptid = tid - 12 * 64;                  // producer thread 0..255

    const float dv = *dvp;

    // ---- prologue: stage rows hc-1..hc+3 (5 rows x 6 wc = 30 cols), all threads
#pragma unroll
    for (int it = 0; it < 15; ++it) {
        const int e  = it * 1024 + tid;
        const int jl = e >> 9;                       // 0..29
        const int sl = e & 511;
        const int row = hc - 1 + jl / CWc;           // <= hc+3 <= 75 < Hn always
        const int wc  = jl % CWc;
        const int ww  = w0 - 1 + wc;
        const bool v  = (row >= 0) && (ww >= 0) && (ww < Wn);
        float4 x = make_float4(0.f, 0.f, 0.f, 0.f);
        if (v) x = *(const float4*)(img + (size_t)((b * Hn + row) * Wn + ww) * COLSZ + sl * 4);
        ushort4 u; u.x = f2bf(x.x); u.y = f2bf(x.y); u.z = f2bf(x.z); u.w = f2bf(x.w);
        *(ushort4*)&colS[(slot6(row) * CWc + wc) * COLSZ
                         + swz_off(sl >> 3, (sl >> 1) & 3) + (sl & 1) * 4] = u;
    }
    __syncthreads();

    for (int p = 0; p < NP; ++p) {
        const int h0 = hc + THp * p;
        const int h  = h0 + ph;                      // consumer pixel row
        const int w  = w0 + pw;

        f32x4  acc[4][2];
        int    sh[9];
        bool   tv[9];
        ushort4 su[36];                              // producer-held staged data
        const int sbase = slot6(h0 + ph - 1);        // slot of row hh at kh=0

        if (consumer) {
            const int bpc = bp[(b * Hn + h) * Wn + w];
#pragma unroll
            for (int kh = 0; kh < 3; ++kh)
#pragma unroll
                for (int kw = 0; kw < 3; ++kw) {
                    const int hh = h - 1 + kh;
                    const int ww = w - 1 + kw;
                    const bool v = (hh >= 0) && (hh < Hn) && (ww >= 0) && (ww < Wn);
                    tv[kh * 3 + kw] = v;
                    sh[kh * 3 + kw] = v ? (bpc - bp[(b * Hn + hh) * Wn + ww]) : 0;
                }
#pragma unroll
            for (int i = 0; i < 4; ++i)
#pragma unroll
                for (int j = 0; j < 2; ++j) acc[i][j] = (f32x4)0.f;
        }

        // r6-proven tap group (kh,kw literal): 12 ds_read_b128 + 24 MFMA
        auto tapg = [&](int kh, int kw) {
            const int t = kh * 3 + kw;
            if (!tv[t]) return;                      // wave-uniform; dv(=0) path
            const int s = sh[t];
            int sl6 = sbase + kh; if (sl6 >= 6) sl6 -= 6;
            const ushort* colp = &colS[(sl6 * CWc + (pw + kw)) * COLSZ];
            const int kkb = t * 3;
            bf16x8 bfr[3][2];
#pragma unroll
            for (int kd = 0; kd < 3; ++kd) {
                bfr[kd][0] = *(const bf16x8*)&kT[((kkb + kd) * Fn + lrow)      * Cn + lgrp * 8];
                bfr[kd][1] = *(const bf16x8*)&kT[((kkb + kd) * Fn + lrow + 16) * Cn + lgrp * 8];
            }
            __builtin_amdgcn_s_setprio(1);
#pragma unroll
            for (int kd = 0; kd < 3; ++kd) {
                const int i1 = 16 + lrow + s + kd - 1;   // in [0,47] (|s|<=15)
                const int o1 = swz_off(i1, lgrp);
                const bf16x8 a1 = *(const bf16x8*)&colp[o1];
                acc[1][0] = __builtin_amdgcn_mfma_f32_16x16x32_bf16(a1, bfr[kd][0], acc[1][0], 0, 0, 0);
                acc[1][1] = __builtin_amdgcn_mfma_f32_16x16x32_bf16(a1, bfr[kd][1], acc[1][1], 0, 0, 0);
                const bf16x8 a2 = *(const bf16x8*)&colp[o1 + 512];
                acc[2][0] = __builtin_amdgcn_mfma_f32_16x16x32_bf16(a2, bfr[kd][0], acc[2][0], 0, 0, 0);
                acc[2][1] = __builtin_amdgcn_mfma_f32_16x16x32_bf16(a2, bfr[kd][1], acc[2][1], 0, 0, 0);
                {
                    const bool vv = (i1 >= 16);          // dt=0 depth-valid
                    bf16x8 a0 = *(const bf16x8*)&colp[vv ? o1 - 512 : o1];
                    if (!vv) a0 = (bf16x8)0;
                    acc[0][0] = __builtin_amdgcn_mfma_f32_16x16x32_bf16(a0, bfr[kd][0], acc[0][0], 0, 0, 0);
                    acc[0][1] = __builtin_amdgcn_mfma_f32_16x16x32_bf16(a0, bfr[kd][1], acc[0][1], 0, 0, 0);
                }
                {
                    const bool vv = (i1 <= 31);          // dt=3 depth-valid
                    bf16x8 a3 = *(const bf16x8*)&colp[vv ? o1 + 1024 : o1];
                    if (!vv) a3 = (bf16x8)0;
                    acc[3][0] = __builtin_amdgcn_mfma_f32_16x16x32_bf16(a3, bfr[kd][0], acc[3][0], 0, 0, 0);
                    acc[3][1] = __builtin_amdgcn_mfma_f32_16x16x32_bf16(a3, bfr[kd][1], acc[3][1], 0, 0, 0);
                }
            }
            __builtin_amdgcn_s_setprio(0);
        };

        // ---- PHASE A: consumers kh=0,1 ; producers load next 3 rows (global->reg)
        if (consumer) {
            tapg(0, 0); tapg(0, 1); tapg(0, 2);
            tapg(1, 0); tapg(1, 1); tapg(1, 2);
        } else if (p < NP - 1) {
            const int r0 = h0 + 4;                   // rows h0+4..h0+6, 18 cols
#pragma unroll
            for (int it = 0; it < 36; ++it) {
                const int jl  = it >> 1;             // 0..17, literal
                const int sl  = (it & 1) * 256 + ptid;
                const int row = r0 + jl / CWc;
                const int wc  = jl % CWc;
                const int ww  = w0 - 1 + wc;
                const bool v  = (row < Hn) && (ww >= 0) && (ww < Wn);
                float4 x = make_float4(0.f, 0.f, 0.f, 0.f);
                if (v) x = *(const float4*)(img + (size_t)((b * Hn + row) * Wn + ww) * COLSZ + sl * 4);
                su[it].x = f2bf(x.x); su[it].y = f2bf(x.y);
                su[it].z = f2bf(x.z); su[it].w = f2bf(x.w);
                if (it == 11 || it == 23) __builtin_amdgcn_sched_barrier(0);  // cap MLP ~12
            }
        }
        __syncthreads();   // rows h0-1,h0 now free; phase-B reads rows h0+1..h0+3

        // ---- PHASE B: consumers kh=2 + store ; producers commit (disjoint slots)
        if (consumer) {
            tapg(2, 0); tapg(2, 1); tapg(2, 2);

            if (dv != 0.0f) {   // dead here; keeps semantics general
#pragma unroll
                for (int kh = 0; kh < 3; ++kh)
#pragma unroll
                    for (int kw = 0; kw < 3; ++kw) {
                        const bool sp = tv[kh * 3 + kw];
                        const int  s  = sh[kh * 3 + kw];
                        for (int kd = 0; kd < 3; ++kd) {
                            float ks0 = 0.f, ks1 = 0.f;
                            for (int c = 0; c < Cn; ++c) {
                                const float* kp = kern + (size_t)(((kh * 3 + kw) * 3 + kd) * Cn + c) * Fn;
                                ks0 += kp[lrow];
                                ks1 += kp[16 + lrow];
                            }
                            for (int dt = 0; dt < 4; ++dt)
                                for (int j = 0; j < 4; ++j) {
                                    const int d   = dt * 16 + lgrp * 4 + j;
                                    const int idx = d + s + kd - 1;
                                    const bool valid = sp && (idx >= 0) && (idx < Dn);
                                    if (!valid) { acc[dt][0][j] += dv * ks0; acc[dt][1][j] += dv * ks1; }
                                }
                        }
                    }
            }

            const size_t pixbase = ((size_t)(b * Hn + h) * Wn + w) * (Dn * Fn);
#pragma unroll
            for (int dt = 0; dt < 4; ++dt)
#pragma unroll
                for (int ft = 0; ft < 2; ++ft)
#pragma unroll
                    for (int j = 0; j < 4; ++j) {
                        const int d = dt * 16 + lgrp * 4 + j;
                        const int f = ft * 16 + lrow;
                        out[pixbase + d * Fn + f] = acc[dt][ft][j];
                    }
        } else if (p < NP - 1) {
            const int r0 = h0 + 4;
#pragma unroll
            for (int it = 0; it < 36; ++it) {
                const int jl  = it >> 1;
                const int sl  = (it & 1) * 256 + ptid;
                const int row = r0 + jl / CWc;
                const int wc  = jl % CWc;
                *(ushort4*)&colS[(slot6(row) * CWc + wc) * COLSZ
                                 + swz_off(sl >> 3, (sl >> 1) & 3) + (sl & 1) * 4] = su[it];
            }
        }
        __syncthreads();   // committed rows visible before next patch's phase A
    }
}

extern "C" void kernel_launch(void* const* d_in, const int* in_sizes, int n_in,
                              void* d_out, int out_size, void* d_ws, size_t ws_size,
                              hipStream_t stream) {
    const float* img  = (const float*)d_in[0];
    const int*   bp   = (const int*)d_in[1];
    const float* kern = (const float*)d_in[2];
    const float* dvp  = (const float*)d_in[3];
    float* out = (float*)d_out;
    ushort* kT = (ushort*)d_ws;                      // 27*32*32*2 = 55296 B

    hipLaunchKernelGGL(prep_kT, dim3(108), dim3(256), 0, stream, kern, kT);

    const int nblk = Bn * (Hn / (THp * NP)) * (Wn / TWp);   // 2*4*32 = 256 (1/CU)
    hipLaunchKernelGGL(sconv3d_pc, dim3(nblk), dim3(1024), 0, stream,
                       img, bp, kern, kT, dvp, out);
}

// Round 10
// 186.220 us; speedup vs baseline: 5.8311x; 5.2185x over previous
//
#include <hip/hip_runtime.h>
#include <hip/hip_bf16.h>

// B=2, H=96, W=128, D=64, C=32, F=32, kernel 3x3x3, pad 1 in h/w, depth-shifted.
#define Bn 2
#define Hn 96
#define Wn 128
#define Dn 64
#define Cn 32
#define Fn 32
#define TH 2                 // patch: 2 h-rows
#define TW 8                 // patch: 8 w-cols  -> 16 pixels, one per wave
#define CW (TW + 2)          // 10 staged w-cols
#define NCOLS (4 * CW)       // 4 h-rows x 10 w-cols = 40 cols x 4KB = 160KB LDS
#define COLSZ (Dn * Cn)      // 2048 shorts per column

typedef short bf16x8 __attribute__((ext_vector_type(8)));
typedef float f32x4  __attribute__((ext_vector_type(4)));

__device__ __forceinline__ ushort f2bf(float x) {
    __hip_bfloat16 h = __float2bfloat16(x);   // RNE
    return *reinterpret_cast<ushort*>(&h);
}

// Rows are 32 shorts (64B) = 4 slots of 16B. slot' = slot ^ ((r>>1)&3):
// 16 consecutive rows at one slot spread over all 8 bank-quads (2-way = free).
// XOR term invariant under row += 16 -> fragment offsets step by +-512 shorts.
__device__ __forceinline__ int swz_off(int r, int slot) {
    return r * 32 + ((slot ^ ((r >> 1) & 3)) << 3);
}

// ---- prep: kT[30][f][c] bf16; taps 0..26 = transpose of kern, taps 27..29 = 0
// (tap 27 is the "invalid tap" target: B-fragment becomes zero, no branches)
__global__ void prep_kT(const float* __restrict__ kern, ushort* __restrict__ kT) {
    const int e = blockIdx.x * 256 + threadIdx.x;    // 30*1024 = 30720
    if (e >= 30 * Cn * Fn) return;
    const int c  = e & 31;
    const int f  = (e >> 5) & 31;
    const int kk = e >> 10;
    kT[e] = (kk < 27) ? f2bf(kern[kk * (Cn * Fn) + c * Fn + f]) : (ushort)0;
}

__global__ __launch_bounds__(1024, 4) void sconv3d_mfma(
    const float*  __restrict__ img,   // [B,H,W,D,C]
    const int*    __restrict__ bp,    // [B,H,W]
    const float*  __restrict__ kern,  // [3,3,3,C,F] (fp32, dv path only)
    const ushort* __restrict__ kT,    // [30][F][C] bf16
    const float*  __restrict__ dvp,
    float*        __restrict__ out)   // [B,H,W,D,F]
{
    // 40 halo columns, bf16 [col][d 0..63][c], swizzled 16B slots.
    __shared__ ushort colS[NCOLS * COLSZ];           // 163840 B

    const int blk = blockIdx.x;
    const int wt  = blk % (Wn / TW);
    const int ht  = (blk / (Wn / TW)) % (Hn / TH);
    const int b   = blk / ((Wn / TW) * (Hn / TH));
    const int h0  = ht * TH;
    const int w0  = wt * TW;

    const int tid  = threadIdx.x;
    const int lane = tid & 63;
    const int wave = tid >> 6;                       // 0..15
    const int ph   = wave >> 3;                      // 0..1
    const int pw   = wave & 7;                       // 0..7
    const int h    = h0 + ph;
    const int w    = w0 + pw;

    const int lrow = lane & 15;                      // A row (d in 16) / B f-col
    const int lgrp = lane >> 4;                      // 16B k-slot (c-block)

    const float dv  = *dvp;
    const int   bpc = bp[(b * Hn + h) * Wn + w];

    // ---- per-wave tap shifts & validity (latency overlaps the staging below)
    int  sh[9];
    bool tv[9];
#pragma unroll
    for (int kh = 0; kh < 3; ++kh)
#pragma unroll
        for (int kw = 0; kw < 3; ++kw) {
            const int hh = h - 1 + kh;
            const int ww = w - 1 + kw;
            const bool v = (hh >= 0) && (hh < Hn) && (ww >= 0) && (ww < Wn);
            tv[kh * 3 + kw] = v;
            sh[kh * 3 + kw] = v ? (bpc - bp[(b * Hn + hh) * Wn + ww]) : 0;
        }

    // ---- stage all 40 halo columns once (fp32 -> bf16, swizzled); OOB -> zeros
#pragma unroll
    for (int it = 0; it < 20; ++it) {
        const int e  = it * 1024 + tid;
        const int j  = e >> 9;                       // col 0..39
        const int sl = e & 511;
        const int hh = h0 - 1 + j / CW;
        const int ww = w0 - 1 + j % CW;
        const bool v = (hh >= 0) && (hh < Hn) && (ww >= 0) && (ww < Wn);
        float4 x = make_float4(0.f, 0.f, 0.f, 0.f);
        if (v) x = *(const float4*)(img +
                     (size_t)((b * Hn + hh) * Wn + ww) * COLSZ + sl * 4);
        ushort4 u;
        u.x = f2bf(x.x); u.y = f2bf(x.y); u.z = f2bf(x.z); u.w = f2bf(x.w);
        *(ushort4*)&colS[j * COLSZ
                         + swz_off(sl >> 3, (sl >> 1) & 3) + (sl & 1) * 4] = u;
    }
    __syncthreads();   // the ONLY barrier

    f32x4 acc[4][2];
#pragma unroll
    for (int i = 0; i < 4; ++i)
#pragma unroll
        for (int j = 0; j < 2; ++j) acc[i][j] = (f32x4)0.f;

    // ---- branchless straight-line compute: 9 tap groups, 216 MFMA per wave.
    // Invalid taps read the ZERO tap (27) of kT -> B = 0, contribution = 0.
#pragma unroll
    for (int kh = 0; kh < 3; ++kh) {
#pragma unroll
        for (int kw = 0; kw < 3; ++kw) {
            const int t    = kh * 3 + kw;
            const int s    = sh[t];
            const int kkb  = tv[t] ? t * 3 : 27;     // zero-weight tap if invalid
            const ushort* colp = &colS[((ph + kh) * CW + (pw + kw)) * COLSZ];
            // hoist the 6 B-fragments for this tap group (L1/L2-resident kT)
            bf16x8 bfr[3][2];
#pragma unroll
            for (int kd = 0; kd < 3; ++kd) {
                bfr[kd][0] = *(const bf16x8*)&kT[((kkb + kd) * Fn + lrow)      * Cn + lgrp * 8];
                bfr[kd][1] = *(const bf16x8*)&kT[((kkb + kd) * Fn + lrow + 16) * Cn + lgrp * 8];
            }
            __builtin_amdgcn_s_setprio(1);
#pragma unroll
            for (int kd = 0; kd < 3; ++kd) {
                const int i1 = 16 + lrow + s + kd - 1;   // in [0,47] (|s|<=15)
                const int o1 = swz_off(i1, lgrp);
                // dt=1, dt=2: always depth-valid, unconditional
                const bf16x8 a1 = *(const bf16x8*)&colp[o1];
                acc[1][0] = __builtin_amdgcn_mfma_f32_16x16x32_bf16(a1, bfr[kd][0], acc[1][0], 0, 0, 0);
                acc[1][1] = __builtin_amdgcn_mfma_f32_16x16x32_bf16(a1, bfr[kd][1], acc[1][1], 0, 0, 0);
                const bf16x8 a2 = *(const bf16x8*)&colp[o1 + 512];
                acc[2][0] = __builtin_amdgcn_mfma_f32_16x16x32_bf16(a2, bfr[kd][0], acc[2][0], 0, 0, 0);
                acc[2][1] = __builtin_amdgcn_mfma_f32_16x16x32_bf16(a2, bfr[kd][1], acc[2][1], 0, 0, 0);
                // dt=0: valid iff i1>=16
                {
                    const bool vv = (i1 >= 16);
                    bf16x8 a0 = *(const bf16x8*)&colp[vv ? o1 - 512 : o1];
                    if (!vv) a0 = (bf16x8)0;
                    acc[0][0] = __builtin_amdgcn_mfma_f32_16x16x32_bf16(a0, bfr[kd][0], acc[0][0], 0, 0, 0);
                    acc[0][1] = __builtin_amdgcn_mfma_f32_16x16x32_bf16(a0, bfr[kd][1], acc[0][1], 0, 0, 0);
                }
                // dt=3: valid iff i1<=31
                {
                    const bool vv = (i1 <= 31);
                    bf16x8 a3 = *(const bf16x8*)&colp[vv ? o1 + 1024 : o1];
                    if (!vv) a3 = (bf16x8)0;
                    acc[3][0] = __builtin_amdgcn_mfma_f32_16x16x32_bf16(a3, bfr[kd][0], acc[3][0], 0, 0, 0);
                    acc[3][1] = __builtin_amdgcn_mfma_f32_16x16x32_bf16(a3, bfr[kd][1], acc[3][1], 0, 0, 0);
                }
            }
            __builtin_amdgcn_s_setprio(0);
        }
    }

    // ---- dv != 0 correction (dead for this benchmark; keeps semantics general)
    if (dv != 0.0f) {
#pragma unroll
        for (int kh = 0; kh < 3; ++kh)
#pragma unroll
            for (int kw = 0; kw < 3; ++kw) {
                const bool sp = tv[kh * 3 + kw];
                const int  s  = sh[kh * 3 + kw];
                for (int kd = 0; kd < 3; ++kd) {
                    float ks0 = 0.f, ks1 = 0.f;
                    for (int c = 0; c < Cn; ++c) {
                        const float* kp = kern + (size_t)(((kh * 3 + kw) * 3 + kd) * Cn + c) * Fn;
                        ks0 += kp[lrow];
                        ks1 += kp[16 + lrow];
                    }
                    for (int dt = 0; dt < 4; ++dt)
                        for (int j = 0; j < 4; ++j) {
                            const int d   = dt * 16 + lgrp * 4 + j;
                            const int idx = d + s + kd - 1;
                            const bool valid = sp && (idx >= 0) && (idx < Dn);
                            if (!valid) { acc[dt][0][j] += dv * ks0; acc[dt][1][j] += dv * ks1; }
                        }
                }
            }
    }

    // ---- epilogue: D lane l reg j -> d = dt*16 + lgrp*4 + j, f = ft*16 + lrow
    const size_t pixbase = ((size_t)(b * Hn + h) * Wn + w) * (Dn * Fn);
#pragma unroll
    for (int dt = 0; dt < 4; ++dt)
#pragma unroll
        for (int ft = 0; ft < 2; ++ft)
#pragma unroll
            for (int j = 0; j < 4; ++j) {
                const int d = dt * 16 + lgrp * 4 + j;
                const int f = ft * 16 + lrow;
                out[pixbase + d * Fn + f] = acc[dt][ft][j];
            }
}

extern "C" void kernel_launch(void* const* d_in, const int* in_sizes, int n_in,
                              void* d_out, int out_size, void* d_ws, size_t ws_size,
                              hipStream_t stream) {
    const float* img  = (const float*)d_in[0];
    const int*   bp   = (const int*)d_in[1];
    const float* kern = (const float*)d_in[2];
    const float* dvp  = (const float*)d_in[3];
    float* out = (float*)d_out;
    ushort* kT = (ushort*)d_ws;                      // 30*32*32*2 = 61440 B

    hipLaunchKernelGGL(prep_kT, dim3(120), dim3(256), 0, stream, kern, kT);

    const int nblk = Bn * (Hn / TH) * (Wn / TW);     // 2*48*16 = 1536
    hipLaunchKernelGGL(sconv3d_mfma, dim3(nblk), dim3(1024), 0, stream,
                       img, bp, kern, kT, dvp, out);
}